// Round 6
// baseline (786.531 us; speedup 1.0000x reference)
//
#include <hip/hip_runtime.h>

// DeepCNF: 5x conv1d(K=11)+tanh -> 1x1 conv to 8 tags -> CRF NLL (sum over batch).
// B=128 T=1024 IN=42 HID=256 K=11 NTAGS=8.
// Inter-layer H format: bf16, row = (b*T+t)*256 shorts, within-row 16B chunks
// stored at position (chunk ^ (t&7)) -- global_load_lds (linear dest) +
// XOR-swizzled ds_read_b128 is conflict-free (both-sides swizzle).
// Conv block = 128 timesteps x 256 co, 8 waves (2 t-halves x 4 co), 70.6KB LDS.
// B-fragment coc = n*4 + wc: at any instant all 8 waves read the same 4KB of
// packed weights (wr-pairs identical addresses) -> L1-served, ~4x less L2.
// conv4 fuses the emission projection via LDS partial reduce (no atomics).
// CRF: log-semiring segment matrix products (32 segments of 32 steps).

#define B_ 128
#define T_ 1024
#define IN_DIM_ 42
#define HID_ 256
#define KW_ 11
#define NTAGS_ 8
#define SEG_ 32
#define SEGL_ (T_ / SEG_)   // 32

typedef __bf16 bf16x8 __attribute__((ext_vector_type(8)));
typedef float f32x4 __attribute__((ext_vector_type(4)));
typedef short s16x8 __attribute__((ext_vector_type(8)));

__device__ __forceinline__ unsigned short f2bf(float f) {
    unsigned u = __builtin_bit_cast(unsigned, f);
    u += 0x7FFFu + ((u >> 16) & 1u);   // RNE
    return (unsigned short)(u >> 16);
}
__device__ __forceinline__ float fast_tanh(float x) {
    float e = __expf(2.f * x);          // inf/0 saturate to +-1 correctly
    return 1.f - 2.f / (e + 1.f);
}

// ---------------------------------------------------------------------------
// Pack all 5 conv weight tensors fp32 -> bf16 MFMA B-fragments in one launch.
// Fragment-group order it = cic*KW + k:
// wp[((it*16+coc)*64+lane)*8+e] = w[coc*16+(lane&15)][cic*32+(lane>>4)*8+e][k]
// Layers contiguous: [SZ0][SZN][SZN][SZN][SZN].
// ---------------------------------------------------------------------------
#define SZ0_ (KW_ * 2 * 16 * 512)
#define SZN_ (KW_ * 8 * 16 * 512)

__global__ void pack_all(const float* __restrict__ w0, const float* __restrict__ w1,
                         const float* __restrict__ w2, const float* __restrict__ w3,
                         const float* __restrict__ w4, unsigned short* __restrict__ wp) {
    const int total = SZ0_ + 4 * SZN_;
    for (int idx = blockIdx.x * 256 + threadIdx.x; idx < total;
         idx += gridDim.x * 256) {
        const float* w;
        int C_in, loc;
        if (idx < SZ0_) { w = w0; C_in = IN_DIM_; loc = idx; }
        else {
            int r = idx - SZ0_;
            int L = r / SZN_;
            loc = r - L * SZN_;
            w = (L == 0) ? w1 : (L == 1) ? w2 : (L == 2) ? w3 : w4;
            C_in = HID_;
        }
        int e    = loc & 7;
        int lane = (loc >> 3) & 63;
        int coc  = (loc >> 9) & 15;
        int rest = loc >> 13;          // it = cic*KW_ + k
        int cic  = rest / KW_;
        int k    = rest - cic * KW_;
        int co = coc * 16 + (lane & 15);
        int ci = cic * 32 + (lane >> 4) * 8 + e;
        float v = (ci < C_in) ? w[(co * C_in + ci) * KW_ + k] : 0.f;
        wp[idx] = f2bf(v);
    }
}

// ---------------------------------------------------------------------------
// Conv layer, implicit GEMM. Block = (batch b, 128 t) x 256 co, 8 waves =
// 2 t-halves (wr) x 4 co-slots (wc); wave tile 64t x 64co, 16x16x32 MFMA.
// coc = n*4 + wc so concurrent waves share B cache lines.
// LAST: fused emission projection via LDS partial reduce (no atomics).
// ---------------------------------------------------------------------------
template <int CIN, bool FIRST, bool LAST>
__global__ __launch_bounds__(512, 4)
void conv_kernel(const void* __restrict__ in_, const unsigned short* __restrict__ wpack,
                 const float* __restrict__ bias, unsigned short* __restrict__ out,
                 const float* __restrict__ w_out, float* __restrict__ emout) {
    constexpr int NCIC = CIN / 32;          // 2 or 8
    constexpr int ROWS = 138;               // 128 + 2*5 halo
    extern __shared__ unsigned short lds[]; // [ROWS][CIN]

    const int tid  = threadIdx.x;
    const int wave = tid >> 6;
    const int lane = tid & 63;
    const int l15  = lane & 15;
    const int lhi  = lane >> 4;
    const int wr   = wave >> 2;             // t-half
    const int wc   = wave & 3;              // co-slot
    const int b    = blockIdx.x >> 3;
    const int t0   = (blockIdx.x & 7) * 128;

    if (FIRST) {
        const float* x = (const float*)in_;
        for (int u = tid; u < ROWS * (CIN / 8); u += 512) {
            int r = u >> 3, c = u & (CIN / 8 - 1);
            int gt = t0 - 5 + r;
            s16x8 v = {0, 0, 0, 0, 0, 0, 0, 0};
            if (gt >= 0 && gt < T_) {
#pragma unroll
                for (int j = 0; j < 8; ++j) {
                    int ci = c * 8 + j;
                    v[j] = (ci < IN_DIM_)
                               ? (short)f2bf(x[((size_t)b * T_ + gt) * IN_DIM_ + ci])
                               : (short)0;
                }
            }
            int p = c ^ ((r + 3) & 7);
            *(s16x8*)&lds[r * CIN + p * 8] = v;
        }
        __syncthreads();
    } else {
        const unsigned short* Hin = (const unsigned short*)in_;
        for (int r0 = wave * 2; r0 < ROWS; r0 += 16) {
            int r  = r0 + (lane >> 5);
            int gt = t0 - 5 + r;
            gt = gt < 0 ? 0 : (gt >= T_ ? T_ - 1 : gt);   // clamp; zeroed below
            const unsigned short* src =
                Hin + ((size_t)b * T_ + gt) * CIN + (lane & 31) * 8;
            __builtin_amdgcn_global_load_lds(
                (const __attribute__((address_space(1))) void*)src,
                (__attribute__((address_space(3))) void*)&lds[r0 * CIN], 16, 0, 0);
        }
        __syncthreads();
        if (t0 == 0) {
            for (int u = tid; u < 5 * (CIN / 2); u += 512)
                ((unsigned*)lds)[u] = 0;                  // rows 0..4
        }
        if (t0 == T_ - 128) {
            for (int u = tid; u < 5 * (CIN / 2); u += 512)
                ((unsigned*)&lds[133 * CIN])[u] = 0;      // rows 133..137
        }
        __syncthreads();
    }

    f32x4 acc[4][4];
#pragma unroll
    for (int tf = 0; tf < 4; ++tf)
#pragma unroll
        for (int n = 0; n < 4; ++n) acc[tf][n] = (f32x4){0.f, 0.f, 0.f, 0.f};

    // B fragment (it, n): wpIt[it*8192 + n*2048]  (coc = n*4 + wc)
    const unsigned short* wpIt = wpack + wc * 512 + lane * 8;
    const int arow = (wr * 64 + l15) * CIN;
    const int l153 = l15 + 3;

    s16x8 Bf0[4], Bf1[4];
#pragma unroll
    for (int n = 0; n < 4; ++n) Bf0[n] = *(const s16x8*)&wpIt[n * 2048];

#define PREF(BUF, nkk)                                                         \
    {                                                                          \
        _Pragma("unroll") for (int n = 0; n < 4; ++n) BUF[n] =                 \
            *(const s16x8*)&wpIt[(nkk) * 8192 + n * 2048];                     \
    }

#define CMP(BUF, kk)                                                           \
    {                                                                          \
        const int k_ = (kk) % KW_;                                             \
        const int q_ = q0 + ((kk) / KW_) * 4;                                  \
        int key_ = (l153 + k_) & 7;                                            \
        int ao_  = arow + ((q_ ^ key_) << 3);                                  \
        s16x8 a0 = *(const s16x8*)&lds[ao_ + (0 * 16 + k_) * CIN];             \
        s16x8 a1 = *(const s16x8*)&lds[ao_ + (1 * 16 + k_) * CIN];             \
        s16x8 a2 = *(const s16x8*)&lds[ao_ + (2 * 16 + k_) * CIN];             \
        s16x8 a3 = *(const s16x8*)&lds[ao_ + (3 * 16 + k_) * CIN];             \
        __builtin_amdgcn_s_setprio(1);                                         \
        _Pragma("unroll") for (int n = 0; n < 4; ++n) {                        \
            bf16x8 bb = __builtin_bit_cast(bf16x8, BUF[n]);                    \
            acc[0][n] = __builtin_amdgcn_mfma_f32_16x16x32_bf16(               \
                __builtin_bit_cast(bf16x8, a0), bb, acc[0][n], 0, 0, 0);       \
            acc[1][n] = __builtin_amdgcn_mfma_f32_16x16x32_bf16(               \
                __builtin_bit_cast(bf16x8, a1), bb, acc[1][n], 0, 0, 0);       \
            acc[2][n] = __builtin_amdgcn_mfma_f32_16x16x32_bf16(               \
                __builtin_bit_cast(bf16x8, a2), bb, acc[2][n], 0, 0, 0);       \
            acc[3][n] = __builtin_amdgcn_mfma_f32_16x16x32_bf16(               \
                __builtin_bit_cast(bf16x8, a3), bb, acc[3][n], 0, 0, 0);       \
        }                                                                      \
        __builtin_amdgcn_s_setprio(0);                                         \
    }

    int q0 = lhi;
    for (int cic2 = 0; cic2 < NCIC; cic2 += 2) {
#pragma unroll
        for (int kk = 0; kk < 2 * KW_; ++kk) {
            if ((kk & 1) == 0) {
                PREF(Bf1, kk + 1);
                CMP(Bf0, kk);
            } else {
                PREF(Bf0, kk + 1);   // kk==21 -> next cic2's it0 (or tail slack)
                CMP(Bf1, kk);
            }
        }
        wpIt += 2 * KW_ * 8192;
        q0 += 8;
    }
#undef PREF
#undef CMP

    if constexpr (!LAST) {
        // epilogue: bias + tanh -> bf16, stored chunk-swizzled by (t&7).
#pragma unroll
        for (int n = 0; n < 4; ++n) {
            int co = n * 64 + wc * 16 + l15;
            float bv = bias[co];
#pragma unroll
            for (int tf = 0; tf < 4; ++tf) {
#pragma unroll
                for (int r4 = 0; r4 < 4; ++r4) {
                    int t = t0 + wr * 64 + tf * 16 + lhi * 4 + r4;
                    float v = fast_tanh(acc[tf][n][r4] + bv);
                    int pos = (co >> 3) ^ (t & 7);
                    out[((size_t)b * T_ + t) * HID_ + pos * 8 + (co & 7)] = f2bf(v);
                }
            }
        }
    } else {
        // fused emissions: wave partial over its 64 co -> LDS -> block reduce
        // over wc -> one coalesced 4KB store. No atomics.
        float wv[4][NTAGS_], bvn[4];
#pragma unroll
        for (int n = 0; n < 4; ++n) {
            int co = n * 64 + wc * 16 + l15;
            bvn[n] = bias[co];
#pragma unroll
            for (int tg = 0; tg < NTAGS_; ++tg) wv[n][tg] = w_out[tg * HID_ + co];
        }
        __syncthreads();                 // A-tile reads done; reuse LDS
        float* pbuf = (float*)lds;       // [4 wc][128 t][8 tg] = 16 KB
#pragma unroll
        for (int tf = 0; tf < 4; ++tf) {
#pragma unroll
            for (int r4 = 0; r4 < 4; ++r4) {
                float h[4];
#pragma unroll
                for (int n = 0; n < 4; ++n)
                    h[n] = fast_tanh(acc[tf][n][r4] + bvn[n]);
                float pt[NTAGS_];
#pragma unroll
                for (int tg = 0; tg < NTAGS_; ++tg)
                    pt[tg] = h[0] * wv[0][tg] + h[1] * wv[1][tg] +
                             h[2] * wv[2][tg] + h[3] * wv[3][tg];
#pragma unroll
                for (int off = 8; off; off >>= 1)
#pragma unroll
                    for (int tg = 0; tg < NTAGS_; ++tg)
                        pt[tg] += __shfl_down(pt[tg], off);
                if (l15 == 0) {
                    int tloc = wr * 64 + tf * 16 + lhi * 4 + r4;
                    f32x4 lo = {pt[0], pt[1], pt[2], pt[3]};
                    f32x4 hi = {pt[4], pt[5], pt[6], pt[7]};
                    *(f32x4*)&pbuf[(wc * 128 + tloc) * 8]     = lo;
                    *(f32x4*)&pbuf[(wc * 128 + tloc) * 8 + 4] = hi;
                }
            }
        }
        __syncthreads();
        for (int u = tid; u < 128 * NTAGS_; u += 512) {
            float s = pbuf[u] + pbuf[1024 + u] + pbuf[2048 + u] + pbuf[3072 + u];
            emout[((size_t)b * T_ + t0) * NTAGS_ + u] = s;
        }
    }
}

// ---------------------------------------------------------------------------
// CRF segment kernel: wave per (b, s). Lane (i=lane>>3, j=lane&7) holds
// M[i][j], lse-product of S_t[i][j] = tr[i][j] + em[b,t,j] + bo[j] over the
// segment (segment 0 starts at t=1).
// ---------------------------------------------------------------------------
__global__ __launch_bounds__(256)
void crf_seg_kernel(const float* __restrict__ em, const float* __restrict__ tr,
                    const float* __restrict__ bo, float* __restrict__ segM) {
    const int gw   = blockIdx.x * 4 + (threadIdx.x >> 6);
    const int b    = gw >> 5;
    const int s    = gw & 31;
    const int lane = threadIdx.x & 63;
    const int i    = lane >> 3;
    const int j    = lane & 7;
    const float* emb = em + (size_t)b * T_ * NTAGS_;
    const float boj = bo[j];

    float tc[8];
#pragma unroll
    for (int k = 0; k < 8; ++k) tc[k] = tr[k * 8 + j];

    const int tb = (s == 0) ? 1 : s * SEGL_;
    const int te = (s + 1) * SEGL_;

    float m = tr[i * 8 + j] + emb[tb * 8 + j] + boj;
    for (int t = tb + 1; t < te; ++t) {
        float emt = emb[t * 8 + j] + boj;
        float v[8];
#pragma unroll
        for (int k = 0; k < 8; ++k) v[k] = __shfl(m, (lane & 56) + k) + tc[k];
        float mx = fmaxf(fmaxf(fmaxf(v[0], v[1]), fmaxf(v[2], v[3])),
                         fmaxf(fmaxf(v[4], v[5]), fmaxf(v[6], v[7])));
        float sm = 0.f;
#pragma unroll
        for (int k = 0; k < 8; ++k) sm += __expf(v[k] - mx);
        m = mx + __logf(sm) + emt;
    }
    segM[(size_t)gw * 64 + lane] = m;
}

// ---------------------------------------------------------------------------
// CRF combine: one wave per batch. Numerator + 32-segment fold (segM in LDS).
// ---------------------------------------------------------------------------
__global__ __launch_bounds__(64)
void crf_kernel(const float* __restrict__ em, const float* __restrict__ segM,
                const int* __restrict__ tags,
                const float* __restrict__ st, const float* __restrict__ et,
                const float* __restrict__ tr, const float* __restrict__ bo,
                float* __restrict__ outp) {
    __shared__ float sM[SEG_ * 64];
    const int b    = blockIdx.x;
    const int lane = threadIdx.x;
    const float* emb = em + (size_t)b * T_ * NTAGS_;
    const int*   tg  = tags + (size_t)b * T_;

    for (int u = lane; u < SEG_ * 64; u += 64)
        sM[u] = segM[(size_t)b * SEG_ * 64 + u];

    const float breg = bo[lane & 7];

    float num = 0.f;
    for (int t = 1 + lane; t < T_; t += 64) {
        int pt = tg[t - 1], ct = tg[t];
        num += tr[pt * NTAGS_ + ct] + emb[t * NTAGS_ + ct] + __shfl(breg, ct);
    }
#pragma unroll
    for (int off = 32; off; off >>= 1) num += __shfl_down(num, off);
    int tgf = tg[0], tgl = tg[T_ - 1];
    float bo_f = __shfl(breg, tgf);
    float score = 0.f;
    if (lane == 0)
        score = num + st[tgf] + emb[tgf] + bo_f + et[tgl];

    __syncthreads();

    // denominator: alpha0 -> fold 32 segment matrices (j = lane&7)
    const int j = lane & 7;
    float alpha = st[j] + emb[j] + breg;
    for (int sgm = 0; sgm < SEG_; ++sgm) {
        const float* M = &sM[sgm * 64];
        float v[8];
#pragma unroll
        for (int i = 0; i < 8; ++i) v[i] = __shfl(alpha, i) + M[i * 8 + j];
        float mx = fmaxf(fmaxf(fmaxf(v[0], v[1]), fmaxf(v[2], v[3])),
                         fmaxf(fmaxf(v[4], v[5]), fmaxf(v[6], v[7])));
        float sm = 0.f;
#pragma unroll
        for (int i = 0; i < 8; ++i) sm += __expf(v[i] - mx);
        alpha = mx + __logf(sm);
    }
    float vj = alpha + et[j];
    float w[8];
#pragma unroll
    for (int i = 0; i < 8; ++i) w[i] = __shfl(vj, i);
    float m2 = w[0];
#pragma unroll
    for (int i = 1; i < 8; ++i) m2 = fmaxf(m2, w[i]);
    float s2 = 0.f;
#pragma unroll
    for (int i = 0; i < 8; ++i) s2 += __expf(w[i] - m2);
    float log_z = m2 + __logf(s2);

    if (lane == 0) atomicAdd(outp, log_z - score);
}

// ---------------------------------------------------------------------------
extern "C" void kernel_launch(void* const* d_in, const int* in_sizes, int n_in,
                              void* d_out, int out_size, void* d_ws, size_t ws_size,
                              hipStream_t stream) {
    const float* x     = (const float*)d_in[0];
    const int*   tags  = (const int*)d_in[3];
    const float* w[5]  = {(const float*)d_in[4], (const float*)d_in[6],
                          (const float*)d_in[8], (const float*)d_in[10],
                          (const float*)d_in[12]};
    const float* bias[5] = {(const float*)d_in[5], (const float*)d_in[7],
                            (const float*)d_in[9], (const float*)d_in[11],
                            (const float*)d_in[13]};
    const float* w_out = (const float*)d_in[14];
    const float* b_out = (const float*)d_in[15];
    const float* st    = (const float*)d_in[16];
    const float* et    = (const float*)d_in[17];
    const float* tr    = (const float*)d_in[18];

    // workspace layout
    unsigned short* H0 = (unsigned short*)d_ws;
    unsigned short* H1 = H0 + (size_t)B_ * T_ * HID_;
    float* em   = (float*)(H1 + (size_t)B_ * T_ * HID_);
    float* segM = em + (size_t)B_ * T_ * NTAGS_;
    unsigned short* wpbase = (unsigned short*)(segM + (size_t)B_ * SEG_ * 64);
    unsigned short* wp[5];
    wp[0] = wpbase;
    wp[1] = wp[0] + SZ0_;
    wp[2] = wp[1] + SZN_;
    wp[3] = wp[2] + SZN_;
    wp[4] = wp[3] + SZN_;
    // B-prefetch overruns a layer's table by <=1 fragment-group + 3 subfrags
    // (~15K shorts); wp[0..3] overrun into the next table, wp[4] into ws slack.

    // dynamic LDS 70656B > 64KB for the HID convs
    hipFuncSetAttribute((const void*)conv_kernel<256, false, false>,
                        hipFuncAttributeMaxDynamicSharedMemorySize, 138 * 256 * 2);
    hipFuncSetAttribute((const void*)conv_kernel<256, false, true>,
                        hipFuncAttributeMaxDynamicSharedMemorySize, 138 * 256 * 2);

    pack_all<<<2048, 256, 0, stream>>>(w[0], w[1], w[2], w[3], w[4], wpbase);

    const int NBLK = B_ * (T_ / 128);   // 1024
    conv_kernel<64, true, false><<<NBLK, 512, 138 * 64 * 2, stream>>>(
        x, wp[0], bias[0], H0, nullptr, nullptr);
    conv_kernel<256, false, false><<<NBLK, 512, 138 * 256 * 2, stream>>>(
        H0, wp[1], bias[1], H1, nullptr, nullptr);
    conv_kernel<256, false, false><<<NBLK, 512, 138 * 256 * 2, stream>>>(
        H1, wp[2], bias[2], H0, nullptr, nullptr);
    conv_kernel<256, false, false><<<NBLK, 512, 138 * 256 * 2, stream>>>(
        H0, wp[3], bias[3], H1, nullptr, nullptr);
    conv_kernel<256, false, true><<<NBLK, 512, 138 * 256 * 2, stream>>>(
        H1, wp[4], bias[4], nullptr, w_out, em);

    crf_seg_kernel<<<B_ * SEG_ / 4, 256, 0, stream>>>(em, tr, b_out, segM);

    hipMemsetAsync(d_out, 0, sizeof(float), stream);
    crf_kernel<<<B_, 64, 0, stream>>>(em, segM, tags, st, et, tr, b_out,
                                      (float*)d_out);
}

// Round 7
// 726.599 us; speedup vs baseline: 1.0825x; 1.0825x over previous
//
#include <hip/hip_runtime.h>

// DeepCNF: 5x conv1d(K=11)+tanh -> 1x1 conv to 8 tags -> CRF NLL (sum over batch).
// B=128 T=1024 IN=42 HID=256 K=11 NTAGS=8.
// Inter-layer H: bf16, row=(b*T+t)*256 shorts, 16B chunks at (chunk ^ (t&7)).
// Mid convs: 256t x 256co megablock, 1 block/CU (136KB LDS), 8 waves
// (wr=t-half x wc=co-quarter), wave tile 128t x 64co, VGPR budget 256:
// acc 128 + B depth-4 (64) + A 6-ahead rotating pipeline (32).
// Weights packed k-major (it2 = k*NCIC + cic) so runtime k-loop keeps all
// register indices static. conv4 fuses emissions via LDS partial reduce.
// CRF: log-semiring segment matrix products (32 segments of 32 steps).

#define B_ 128
#define T_ 1024
#define IN_DIM_ 42
#define HID_ 256
#define KW_ 11
#define NTAGS_ 8
#define SEG_ 32
#define SEGL_ (T_ / SEG_)   // 32

typedef __bf16 bf16x8 __attribute__((ext_vector_type(8)));
typedef float f32x4 __attribute__((ext_vector_type(4)));
typedef short s16x8 __attribute__((ext_vector_type(8)));

__device__ __forceinline__ unsigned short f2bf(float f) {
    unsigned u = __builtin_bit_cast(unsigned, f);
    u += 0x7FFFu + ((u >> 16) & 1u);   // RNE
    return (unsigned short)(u >> 16);
}
__device__ __forceinline__ float fast_tanh(float x) {
    float e = __expf(2.f * x);          // inf/0 saturate to +-1 correctly
    return 1.f - 2.f / (e + 1.f);
}

#define SZ0_ (KW_ * 2 * 16 * 512)
#define SZN_ (KW_ * 8 * 16 * 512)

// ---------------------------------------------------------------------------
// Pack all conv weights fp32 -> bf16 MFMA B-fragments, k-major groups:
// it2 = k*NCIC + cic;  wp[((it2*16+coc)*64+lane)*8+e] =
//   w[coc*16+(lane&15)][cic*32+(lane>>4)*8+e][k]
// ---------------------------------------------------------------------------
__global__ void pack_all(const float* __restrict__ w0, const float* __restrict__ w1,
                         const float* __restrict__ w2, const float* __restrict__ w3,
                         const float* __restrict__ w4, unsigned short* __restrict__ wp) {
    const int total = SZ0_ + 4 * SZN_;
    for (int idx = blockIdx.x * 256 + threadIdx.x; idx < total;
         idx += gridDim.x * 256) {
        const float* w;
        int C_in, loc, cic, k;
        if (idx < SZ0_) {
            w = w0; C_in = IN_DIM_; loc = idx;
            int it2 = loc >> 13; cic = it2 & 1; k = it2 >> 1;
        } else {
            int r = idx - SZ0_;
            int L = r / SZN_;
            loc = r - L * SZN_;
            w = (L == 0) ? w1 : (L == 1) ? w2 : (L == 2) ? w3 : w4;
            C_in = HID_;
            int it2 = loc >> 13; cic = it2 & 7; k = it2 >> 3;
        }
        int e    = loc & 7;
        int lane = (loc >> 3) & 63;
        int coc  = (loc >> 9) & 15;
        int co = coc * 16 + (lane & 15);
        int ci = cic * 32 + (lane >> 4) * 8 + e;
        float v = (ci < C_in) ? w[(co * C_in + ci) * KW_ + k] : 0.f;
        wp[idx] = f2bf(v);
    }
}

// ---------------------------------------------------------------------------
// First conv layer: fp32 x (42ch) input, 128t x 256co block, 8 waves
// (2 t-halves x 4 co-quarters), CIN padded to 64. float2-vectorized staging.
// ---------------------------------------------------------------------------
__global__ __launch_bounds__(512, 4)
void conv_first(const float* __restrict__ x, const unsigned short* __restrict__ wpack,
                const float* __restrict__ bias, unsigned short* __restrict__ out) {
    constexpr int CIN = 64, ROWS = 138;
    __shared__ unsigned short lds[ROWS * CIN];

    const int tid  = threadIdx.x;
    const int wave = tid >> 6;
    const int lane = tid & 63;
    const int l15  = lane & 15;
    const int lhi  = lane >> 4;
    const int wr   = wave >> 2;
    const int wc   = wave & 3;
    const int b    = blockIdx.x >> 3;
    const int t0   = (blockIdx.x & 7) * 128;

    for (int u = tid; u < ROWS * 32; u += 512) {
        int r = u >> 5, m = u & 31;        // m = float2 index, ci0 = 2m
        int gt = t0 - 5 + r;
        unsigned val = 0;
        if (gt >= 0 && gt < T_ && 2 * m < IN_DIM_) {
            float2 f = *(const float2*)&x[((size_t)b * T_ + gt) * IN_DIM_ + 2 * m];
            val = (unsigned)f2bf(f.x) | ((unsigned)f2bf(f.y) << 16);
        }
        int c = m >> 2;
        int p = c ^ ((r + 3) & 7);
        ((unsigned*)lds)[(r * CIN + p * 8) / 2 + (m & 3)] = val;
    }
    __syncthreads();

    f32x4 acc[4][4];
#pragma unroll
    for (int tf = 0; tf < 4; ++tf)
#pragma unroll
        for (int n = 0; n < 4; ++n) acc[tf][n] = (f32x4){0.f, 0.f, 0.f, 0.f};

    const unsigned short* wpq = wpack + (size_t)(wc * 4) * 512 + lane * 8;
    const int arow = (wr * 64 + l15) * CIN;
    const int l153 = l15 + 3;

    s16x8 Bq[2][4];
#pragma unroll
    for (int n = 0; n < 4; ++n) Bq[0][n] = *(const s16x8*)&wpq[n * 512];

#pragma unroll
    for (int k = 0; k < KW_; ++k) {
#pragma unroll
        for (int cic = 0; cic < 2; ++cic) {
            const int it2 = k * 2 + cic;
            const int nxt = it2 + 1;       // overrun into next table: harmless
#pragma unroll
            for (int n = 0; n < 4; ++n)
                Bq[nxt & 1][n] = *(const s16x8*)&wpq[(size_t)nxt * 8192 + n * 512];
            const int key = (l153 + k) & 7;
            const int ao  = arow + (((cic * 4 + lhi) ^ key) << 3);
            s16x8 a0 = *(const s16x8*)&lds[ao + (0 * 16 + k) * CIN];
            s16x8 a1 = *(const s16x8*)&lds[ao + (1 * 16 + k) * CIN];
            s16x8 a2 = *(const s16x8*)&lds[ao + (2 * 16 + k) * CIN];
            s16x8 a3 = *(const s16x8*)&lds[ao + (3 * 16 + k) * CIN];
            __builtin_amdgcn_s_setprio(1);
#pragma unroll
            for (int n = 0; n < 4; ++n) {
                bf16x8 bb = __builtin_bit_cast(bf16x8, Bq[it2 & 1][n]);
                acc[0][n] = __builtin_amdgcn_mfma_f32_16x16x32_bf16(
                    __builtin_bit_cast(bf16x8, a0), bb, acc[0][n], 0, 0, 0);
                acc[1][n] = __builtin_amdgcn_mfma_f32_16x16x32_bf16(
                    __builtin_bit_cast(bf16x8, a1), bb, acc[1][n], 0, 0, 0);
                acc[2][n] = __builtin_amdgcn_mfma_f32_16x16x32_bf16(
                    __builtin_bit_cast(bf16x8, a2), bb, acc[2][n], 0, 0, 0);
                acc[3][n] = __builtin_amdgcn_mfma_f32_16x16x32_bf16(
                    __builtin_bit_cast(bf16x8, a3), bb, acc[3][n], 0, 0, 0);
            }
            __builtin_amdgcn_s_setprio(0);
        }
    }

#pragma unroll
    for (int n = 0; n < 4; ++n) {
        int co = wc * 64 + n * 16 + l15;
        float bv = bias[co];
#pragma unroll
        for (int tf = 0; tf < 4; ++tf) {
#pragma unroll
            for (int r4 = 0; r4 < 4; ++r4) {
                int t = t0 + wr * 64 + tf * 16 + lhi * 4 + r4;
                float v = fast_tanh(acc[tf][n][r4] + bv);
                int pos = (co >> 3) ^ (t & 7);
                out[((size_t)b * T_ + t) * HID_ + pos * 8 + (co & 7)] = f2bf(v);
            }
        }
    }
}

// ---------------------------------------------------------------------------
// Mid conv: 256t x 256co block, 1 block/CU, 8 waves. Wave tile 128t x 64co
// (acc[8][4]). B depth-4 register prefetch (static slots cic&3); A 6-ahead
// rotating 8-slot ds_read pipeline (slot = tf). Runtime k-loop (I-cache),
// all register indices static.
// ---------------------------------------------------------------------------
template <bool LAST>
__global__ __launch_bounds__(512, 2)
void conv_mid(const unsigned short* __restrict__ Hin,
              const unsigned short* __restrict__ wpack,
              const float* __restrict__ bias, unsigned short* __restrict__ out,
              const float* __restrict__ w_out, float* __restrict__ emout) {
    constexpr int CIN = 256, ROWS = 266;
    extern __shared__ unsigned short lds[];   // [266][256] = 136192 B

    const int tid  = threadIdx.x;
    const int wave = tid >> 6;
    const int lane = tid & 63;
    const int l15  = lane & 15;
    const int lhi  = lane >> 4;
    const int wr   = wave >> 2;               // t-half (128)
    const int wc   = wave & 3;                // co-quarter
    const int b    = blockIdx.x >> 2;
    const int t0   = (blockIdx.x & 3) * 256;

    // ---- stage [t0-5, t0+261) (clamped; halo zeroed below) ----
    for (int r0 = wave * 2; r0 < ROWS; r0 += 16) {
        int r  = r0 + (lane >> 5);
        int gt = t0 - 5 + r;
        gt = gt < 0 ? 0 : (gt >= T_ ? T_ - 1 : gt);
        const unsigned short* src =
            Hin + ((size_t)b * T_ + gt) * CIN + (lane & 31) * 8;
        __builtin_amdgcn_global_load_lds(
            (const __attribute__((address_space(1))) void*)src,
            (__attribute__((address_space(3))) void*)&lds[r0 * CIN], 16, 0, 0);
    }
    __syncthreads();
    if (t0 == 0) {
        for (int u = tid; u < 5 * (CIN / 2); u += 512)
            ((unsigned*)lds)[u] = 0;                       // rows 0..4
    }
    if (t0 == T_ - 256) {
        for (int u = tid; u < 5 * (CIN / 2); u += 512)
            ((unsigned*)&lds[261 * CIN])[u] = 0;           // rows 261..265
    }
    __syncthreads();

    f32x4 acc[8][4];
#pragma unroll
    for (int tf = 0; tf < 8; ++tf)
#pragma unroll
        for (int n = 0; n < 4; ++n) acc[tf][n] = (f32x4){0.f, 0.f, 0.f, 0.f};

    const unsigned short* wpq = wpack + (size_t)(wc * 4) * 512 + lane * 8;
    const int arow = (wr * 128 + l15) * CIN;
    const int l153 = l15 + 3;

    s16x8 aq[8];       // rotating A pipeline, slot = stream-pos & 7
    s16x8 Bq[4][4];    // B depth-4, slot = cic & 3

    // B prologue: it2 = 0..3
#pragma unroll
    for (int j = 0; j < 4; ++j)
#pragma unroll
        for (int n = 0; n < 4; ++n)
            Bq[j][n] = *(const s16x8*)&wpq[(size_t)(j * 16 + n) * 512];

    // A prologue: positions 0..5 (k=0, cic=0, tf=0..5)
    {
        const int key0 = l153 & 7;
#pragma unroll
        for (int p = 0; p < 6; ++p)
            aq[p] = *(const s16x8*)&lds[arow + ((lhi ^ key0) << 3) + p * 16 * CIN];
    }

    int key0 = l153 & 7;
    int woff = 4 * 8192;                       // element offset of it2=4 group
#pragma unroll 1
    for (int k = 0; k < KW_; ++k) {
        const int key1 = (key0 + 1) & 7;
        const int ab0  = arow + k * CIN;
        const int ab1  = ab0 + CIN;
#pragma unroll
        for (int cic = 0; cic < 8; ++cic) {
#pragma unroll
            for (int tf = 0; tf < 8; ++tf) {
                // ahead-read for stream position +6
                const int  tfA   = (tf + 6) & 7;
                int        cicA  = cic + (tf >= 2 ? 1 : 0);
                const bool nk    = (cicA == 8);
                if (nk) cicA = 0;
                const int base = nk ? ab1 : ab0;
                const int key  = nk ? key1 : key0;
                aq[tfA] = *(const s16x8*)&lds[base + (((cicA * 4 + lhi) ^ key) << 3)
                                              + tfA * 16 * CIN];
                __builtin_amdgcn_s_setprio(1);
#pragma unroll
                for (int n = 0; n < 4; ++n) {
                    acc[tf][n] = __builtin_amdgcn_mfma_f32_16x16x32_bf16(
                        __builtin_bit_cast(bf16x8, aq[tf]),
                        __builtin_bit_cast(bf16x8, Bq[cic & 3][n]), acc[tf][n],
                        0, 0, 0);
                }
                __builtin_amdgcn_s_setprio(0);
            }
            // B prefetch it2+4 into freed slot (overrun past table: harmless)
#pragma unroll
            for (int n = 0; n < 4; ++n)
                Bq[cic & 3][n] =
                    *(const s16x8*)&wpq[(size_t)woff + cic * 8192 + n * 512];
        }
        key0 = key1;
        woff += 8 * 8192;
    }

    if constexpr (!LAST) {
#pragma unroll
        for (int n = 0; n < 4; ++n) {
            int co = wc * 64 + n * 16 + l15;
            float bv = bias[co];
#pragma unroll
            for (int tf = 0; tf < 8; ++tf) {
#pragma unroll
                for (int r4 = 0; r4 < 4; ++r4) {
                    int t = t0 + wr * 128 + tf * 16 + lhi * 4 + r4;
                    float v = fast_tanh(acc[tf][n][r4] + bv);
                    int pos = (co >> 3) ^ (t & 7);
                    out[((size_t)b * T_ + t) * HID_ + pos * 8 + (co & 7)] = f2bf(v);
                }
            }
        }
    } else {
        // fused emissions: wave partial over its 64 co -> LDS -> reduce over wc
        float wv[4][NTAGS_], bvn[4];
#pragma unroll
        for (int n = 0; n < 4; ++n) {
            int co = wc * 64 + n * 16 + l15;
            bvn[n] = bias[co];
#pragma unroll
            for (int tg = 0; tg < NTAGS_; ++tg) wv[n][tg] = w_out[tg * HID_ + co];
        }
        __syncthreads();                 // A-tile reads done; reuse LDS
        float* pbuf = (float*)lds;       // [4 wc][256 t][8 tg] = 32 KB
#pragma unroll
        for (int tf = 0; tf < 8; ++tf) {
#pragma unroll
            for (int r4 = 0; r4 < 4; ++r4) {
                float h[4];
#pragma unroll
                for (int n = 0; n < 4; ++n)
                    h[n] = fast_tanh(acc[tf][n][r4] + bvn[n]);
                float pt[NTAGS_];
#pragma unroll
                for (int tg = 0; tg < NTAGS_; ++tg)
                    pt[tg] = h[0] * wv[0][tg] + h[1] * wv[1][tg] +
                             h[2] * wv[2][tg] + h[3] * wv[3][tg];
#pragma unroll
                for (int off = 8; off; off >>= 1)
#pragma unroll
                    for (int tg = 0; tg < NTAGS_; ++tg)
                        pt[tg] += __shfl_down(pt[tg], off);
                if (l15 == 0) {
                    int tloc = wr * 128 + tf * 16 + lhi * 4 + r4;
                    f32x4 lo = {pt[0], pt[1], pt[2], pt[3]};
                    f32x4 hi = {pt[4], pt[5], pt[6], pt[7]};
                    *(f32x4*)&pbuf[(wc * 256 + tloc) * 8]     = lo;
                    *(f32x4*)&pbuf[(wc * 256 + tloc) * 8 + 4] = hi;
                }
            }
        }
        __syncthreads();
        for (int u = tid; u < 256 * NTAGS_; u += 512) {
            float s = pbuf[u] + pbuf[2048 + u] + pbuf[4096 + u] + pbuf[6144 + u];
            emout[((size_t)b * T_ + t0) * NTAGS_ + u] = s;
        }
    }
}

// ---------------------------------------------------------------------------
// CRF segment kernel: wave per (b, s). Lane (i=lane>>3, j=lane&7) holds
// M[i][j], lse-product of S_t[i][j] = tr[i][j] + em[b,t,j] + bo[j].
// ---------------------------------------------------------------------------
__global__ __launch_bounds__(256)
void crf_seg_kernel(const float* __restrict__ em, const float* __restrict__ tr,
                    const float* __restrict__ bo, float* __restrict__ segM) {
    const int gw   = blockIdx.x * 4 + (threadIdx.x >> 6);
    const int b    = gw >> 5;
    const int s    = gw & 31;
    const int lane = threadIdx.x & 63;
    const int i    = lane >> 3;
    const int j    = lane & 7;
    const float* emb = em + (size_t)b * T_ * NTAGS_;
    const float boj = bo[j];

    float tc[8];
#pragma unroll
    for (int k = 0; k < 8; ++k) tc[k] = tr[k * 8 + j];

    const int tb = (s == 0) ? 1 : s * SEGL_;
    const int te = (s + 1) * SEGL_;

    float m = tr[i * 8 + j] + emb[tb * 8 + j] + boj;
    for (int t = tb + 1; t < te; ++t) {
        float emt = emb[t * 8 + j] + boj;
        float v[8];
#pragma unroll
        for (int k = 0; k < 8; ++k) v[k] = __shfl(m, (lane & 56) + k) + tc[k];
        float mx = fmaxf(fmaxf(fmaxf(v[0], v[1]), fmaxf(v[2], v[3])),
                         fmaxf(fmaxf(v[4], v[5]), fmaxf(v[6], v[7])));
        float sm = 0.f;
#pragma unroll
        for (int k = 0; k < 8; ++k) sm += __expf(v[k] - mx);
        m = mx + __logf(sm) + emt;
    }
    segM[(size_t)gw * 64 + lane] = m;
}

// ---------------------------------------------------------------------------
// CRF combine: one wave per batch. Numerator + 32-segment fold.
// ---------------------------------------------------------------------------
__global__ __launch_bounds__(64)
void crf_kernel(const float* __restrict__ em, const float* __restrict__ segM,
                const int* __restrict__ tags,
                const float* __restrict__ st, const float* __restrict__ et,
                const float* __restrict__ tr, const float* __restrict__ bo,
                float* __restrict__ outp) {
    __shared__ float sM[SEG_ * 64];
    const int b    = blockIdx.x;
    const int lane = threadIdx.x;
    const float* emb = em + (size_t)b * T_ * NTAGS_;
    const int*   tg  = tags + (size_t)b * T_;

    for (int u = lane; u < SEG_ * 64; u += 64)
        sM[u] = segM[(size_t)b * SEG_ * 64 + u];

    const float breg = bo[lane & 7];

    float num = 0.f;
    for (int t = 1 + lane; t < T_; t += 64) {
        int pt = tg[t - 1], ct = tg[t];
        num += tr[pt * NTAGS_ + ct] + emb[t * NTAGS_ + ct] + __shfl(breg, ct);
    }
#pragma unroll
    for (int off = 32; off; off >>= 1) num += __shfl_down(num, off);
    int tgf = tg[0], tgl = tg[T_ - 1];
    float bo_f = __shfl(breg, tgf);
    float score = 0.f;
    if (lane == 0)
        score = num + st[tgf] + emb[tgf] + bo_f + et[tgl];

    __syncthreads();

    const int j = lane & 7;
    float alpha = st[j] + emb[j] + breg;
    for (int sgm = 0; sgm < SEG_; ++sgm) {
        const float* M = &sM[sgm * 64];
        float v[8];
#pragma unroll
        for (int i = 0; i < 8; ++i) v[i] = __shfl(alpha, i) + M[i * 8 + j];
        float mx = fmaxf(fmaxf(fmaxf(v[0], v[1]), fmaxf(v[2], v[3])),
                         fmaxf(fmaxf(v[4], v[5]), fmaxf(v[6], v[7])));
        float sm = 0.f;
#pragma unroll
        for (int i = 0; i < 8; ++i) sm += __expf(v[i] - mx);
        alpha = mx + __logf(sm);
    }
    float vj = alpha + et[j];
    float w[8];
#pragma unroll
    for (int i = 0; i < 8; ++i) w[i] = __shfl(vj, i);
    float m2 = w[0];
#pragma unroll
    for (int i = 1; i < 8; ++i) m2 = fmaxf(m2, w[i]);
    float s2 = 0.f;
#pragma unroll
    for (int i = 0; i < 8; ++i) s2 += __expf(w[i] - m2);
    float log_z = m2 + __logf(s2);

    if (lane == 0) atomicAdd(outp, log_z - score);
}

// ---------------------------------------------------------------------------
extern "C" void kernel_launch(void* const* d_in, const int* in_sizes, int n_in,
                              void* d_out, int out_size, void* d_ws, size_t ws_size,
                              hipStream_t stream) {
    const float* x     = (const float*)d_in[0];
    const int*   tags  = (const int*)d_in[3];
    const float* w[5]  = {(const float*)d_in[4], (const float*)d_in[6],
                          (const float*)d_in[8], (const float*)d_in[10],
                          (const float*)d_in[12]};
    const float* bias[5] = {(const float*)d_in[5], (const float*)d_in[7],
                            (const float*)d_in[9], (const float*)d_in[11],
                            (const float*)d_in[13]};
    const float* w_out = (const float*)d_in[14];
    const float* b_out = (const float*)d_in[15];
    const float* st    = (const float*)d_in[16];
    const float* et    = (const float*)d_in[17];
    const float* tr    = (const float*)d_in[18];

    // workspace layout: H0, H1, wp tables, em, segM (wp overruns land in em)
    unsigned short* H0 = (unsigned short*)d_ws;
    unsigned short* H1 = H0 + (size_t)B_ * T_ * HID_;
    unsigned short* wpbase = H1 + (size_t)B_ * T_ * HID_;
    unsigned short* wp[5];
    wp[0] = wpbase;
    wp[1] = wp[0] + SZ0_;
    wp[2] = wp[1] + SZN_;
    wp[3] = wp[2] + SZN_;
    wp[4] = wp[3] + SZN_;
    float* em   = (float*)(wp[4] + SZN_);
    float* segM = em + (size_t)B_ * T_ * NTAGS_;

    const int MLDS = 266 * 256 * 2;   // 136192 B dynamic LDS for mid convs
    hipFuncSetAttribute((const void*)conv_mid<false>,
                        hipFuncAttributeMaxDynamicSharedMemorySize, MLDS);
    hipFuncSetAttribute((const void*)conv_mid<true>,
                        hipFuncAttributeMaxDynamicSharedMemorySize, MLDS);

    pack_all<<<2048, 256, 0, stream>>>(w[0], w[1], w[2], w[3], w[4], wpbase);

    conv_first<<<B_ * (T_ / 128), 512, 0, stream>>>(x, wp[0], bias[0], H0);

    const int NBLK = B_ * (T_ / 256);   // 512
    conv_mid<false><<<NBLK, 512, MLDS, stream>>>(H0, wp[1], bias[1], H1,
                                                 nullptr, nullptr);
    conv_mid<false><<<NBLK, 512, MLDS, stream>>>(H1, wp[2], bias[2], H0,
                                                 nullptr, nullptr);
    conv_mid<false><<<NBLK, 512, MLDS, stream>>>(H0, wp[3], bias[3], H1,
                                                 nullptr, nullptr);
    conv_mid<true><<<NBLK, 512, MLDS, stream>>>(H1, wp[4], bias[4], nullptr,
                                                w_out, em);

    crf_seg_kernel<<<B_ * SEG_ / 4, 256, 0, stream>>>(em, tr, b_out, segM);

    hipMemsetAsync(d_out, 0, sizeof(float), stream);
    crf_kernel<<<B_, 64, 0, stream>>>(em, segM, tags, st, et, tr, b_out,
                                      (float*)d_out);
}